// Round 8
// baseline (160.520 us; speedup 1.0000x reference)
//
#include <hip/hip_runtime.h>

#define IMG_W 512
#define IMG_H 512
#define N_IMG 48            // 16 batch * 3 channels
#define TILE_W 64
#define TILE_H 32           // R13: keep 32 (R12's 16 was +75% dur).
#define RAD 5
#define XROWS 48            // 42 halo rows padded to 3 m-tiles of 16
#define XCOLS 84            // R9: 168B row stride -> 16 distinct read start-banks.
#define NBX (IMG_W / TILE_W)   // 8
#define NBY (IMG_H / TILE_H)   // 16

typedef float f32x4v __attribute__((ext_vector_type(4)));
typedef short bf16x8 __attribute__((ext_vector_type(8)));
typedef short bf16x4 __attribute__((ext_vector_type(4)));

// R16: fp32x2 -> packed bf16x2 in 3 VALU ops (2 adds + v_perm_b32) vs ~11 for
// hand-rolled RNE. Round-half-up: identical 0.5-ulp max error to RNE, differs
// only on exact ties. All packed values here are finite non-negative (<~1.2),
// so +0x8000 cannot carry into the inf/NaN exponent range. Pure byte shuffle —
// no inline asm (R9/R10's NaN culprit was the v_cvt_pk asm; not reintroduced).
// perm semantics: dst.byte[i] = sel.byte[i] in 0..3 -> src1.byte[k],
// 4..7 -> src0.byte[k-4]. sel 0x07060302: low16=hi16(ua), high16=hi16(ub).
__device__ inline unsigned int bf16pair(float a, float b) {
    const unsigned int ua = __float_as_uint(a) + 0x8000u;
    const unsigned int ub = __float_as_uint(b) + 0x8000u;
    return __builtin_amdgcn_perm(ub, ua, 0x07060302u);
}

// Scalar RNE (make_frag only — 16 values/thread, off the hot path).
__device__ inline short bf16r(float a) {
    unsigned int u = __float_as_uint(a);
    u = (u + 0x7fffu + ((u >> 16) & 1u)) >> 16;
    return (short)u;
}

// R10/R11: fragment build via closed form (no ssum loop, no divide):
//   w(d) = exp2(-(d-5)^2 * log2e/4.5) * (1/ssum), constants folded.
__device__ inline bf16x8 make_frag(int dbase) {
    bf16x8 f;
    #pragma unroll
    for (int j = 0; j < 8; ++j) {
        const int d = dbase + j;
        const float x = (float)(d - 5);
        const float w = exp2f(-0.32059890f * x * x) * 0.26601246f;
        f[j] = bf16r((d >= 0 && d <= 10) ? w : 0.f);
    }
    return f;
}

// R15: acc is up to 64 slots, each on its own 64B cache line (stride 8
// doubles). slotmask = nslots-1 (pow2). ws_size-guarded on host.
__global__ void ssim_zero_acc(double* acc, int slotmask) {
    const int i = threadIdx.x;
    if (i <= slotmask) acc[i * 8] = 0.0;
}

// NOTE 1 (R3/R4 vs R5): NO __threadfence / fold-in finalize; separate finalize
// kernel is free.
// NOTE 2 (R8): both 11-tap convs on MFMA; banded Gaussian weights in B
// (B[k][n]=wt[k-n-c], closed-form in registers).
// NOTE 3 (R14): YT LDS round-trip deleted; pass1->pass2 hand-off is an
// in-wave shuffle transpose, ONE barrier.
// NOTE 4 (R15): single-address atomicAdd(double) serialized 6144 same-line
// RMWs (~11.3 ns each) — 64 spread slots bought -33 us (95.7 -> 62.8).
// NOTE 5 (R16): VALUBusy hit 66% post-R15 -> packing was ~half of VALU issue;
// perm-based 3-op pack cuts ~500 VALU ops/thread.
__global__ __launch_bounds__(256, 4)
void ssim_main(const float* __restrict__ pred, const float* __restrict__ targ,
               double* __restrict__ acc, int slotmask)
{
    __shared__ __align__(16) unsigned short X[5][XROWS][XCOLS];
    __shared__ float wave_part[4];

    const int tid  = threadIdx.x;
    const int lane = tid & 63;
    const int wv   = tid >> 6;     // wave 0..3
    const int n15  = lane & 15;
    const int q    = lane >> 4;    // 0..3

    const int col0 = blockIdx.x * TILE_W;
    const int row0 = blockIdx.y * TILE_H;
    const bool edge = (blockIdx.x == 0) || (blockIdx.x == NBX - 1);
    const long img = blockIdx.z;
    const float* __restrict__ p = pred + img * (long)(IMG_H * IMG_W);
    const float* __restrict__ t = targ + img * (long)(IMG_H * IMG_W);

    // ---- Phase 0a: issue ALL staging loads (4 slots x {p,t} float4).
    float pv[4][4], tv[4][4];
    #pragma unroll
    for (int s = 0; s < 4; ++s) {
        const int idx = tid + s * 256;
        #pragma unroll
        for (int e = 0; e < 4; ++e) { pv[s][e] = 0.f; tv[s][e] = 0.f; }
        if (idx < XROWS * 20) {
            const int r = idx / 20;
            const int g = idx - r * 20;
            const int gr  = row0 - RAD + r;
            const int gcb = col0 - 8 + 4 * g;
            if (gr >= 0 && gr < IMG_H) {
                const float* __restrict__ prow = p + (long)gr * IMG_W;
                const float* __restrict__ trow = t + (long)gr * IMG_W;
                if (!edge || (gcb >= 0 && gcb + 4 <= IMG_W)) {
                    const float4 a = *(const float4*)&prow[gcb];
                    const float4 b = *(const float4*)&trow[gcb];
                    pv[s][0] = a.x; pv[s][1] = a.y; pv[s][2] = a.z; pv[s][3] = a.w;
                    tv[s][0] = b.x; tv[s][1] = b.y; tv[s][2] = b.z; tv[s][3] = b.w;
                } else {
                    #pragma unroll
                    for (int e = 0; e < 4; ++e) {
                        const int c = gcb + e;
                        if (c >= 0 && c < IMG_W) { pv[s][e] = prow[c]; tv[s][e] = trow[c]; }
                    }
                }
            }
        }
    }

    // B fragments — independent VALU work between load issue and use.
    const bf16x8 Bh = make_frag(q * 8 - n15 - 3);
    const bf16x8 Bv = make_frag(q * 8 - n15);

    // ---- Phase 0b: convert + LDS write. Every element of X cols 0..79 is
    // written (finite) — MFMA reads the full footprint; 0-weight x Inf/NaN
    // would poison accumulators.
    #pragma unroll
    for (int s = 0; s < 4; ++s) {
        const int idx = tid + s * 256;
        if (idx < XROWS * 20) {
            const int r = idx / 20;
            const int g = idx - r * 20;
            const float* P = pv[s];
            const float* T = tv[s];
            *(uint2*)&X[0][r][4 * g] = make_uint2(bf16pair(P[0], P[1]), bf16pair(P[2], P[3]));
            *(uint2*)&X[1][r][4 * g] = make_uint2(bf16pair(T[0], T[1]), bf16pair(T[2], T[3]));
            *(uint2*)&X[2][r][4 * g] = make_uint2(bf16pair(P[0]*P[0], P[1]*P[1]),
                                                  bf16pair(P[2]*P[2], P[3]*P[3]));
            *(uint2*)&X[3][r][4 * g] = make_uint2(bf16pair(T[0]*T[0], T[1]*T[1]),
                                                  bf16pair(T[2]*T[2], T[3]*T[3]));
            *(uint2*)&X[4][r][4 * g] = make_uint2(bf16pair(P[0]*T[0], P[1]*T[1]),
                                                  bf16pair(P[2]*T[2], P[3]*T[3]));
        }
    }
    __syncthreads();   // the ONLY full barrier

    // ---- MFMA pass 1: horizontal conv. Wave wv owns out-col tile wv.
    // A[m][k] = X[mt*16+m][wv*16+k]; D[m][n] = Y[mt*16+m][outcol wv*16+n].
    // Lane (q,n) gets rows q*4+{0..3} of col n, packed as 2 bf16-pair dwords.
    // A-read as 2x ds_read_b64 — 168B rows are 8-aligned only; 16 start banks.
    uint2 yreg[15];
    {
        const f32x4v cz = {0.f, 0.f, 0.f, 0.f};
        int i = 0;
        #pragma unroll
        for (int a = 0; a < 5; ++a) {
            #pragma unroll
            for (int mt = 0; mt < 3; ++mt) {
                const bf16x4 alo = *(const bf16x4*)&X[a][mt * 16 + n15][wv * 16 + 8 * q];
                const bf16x4 ahi = *(const bf16x4*)&X[a][mt * 16 + n15][wv * 16 + 8 * q + 4];
                const bf16x8 A = {alo[0], alo[1], alo[2], alo[3],
                                  ahi[0], ahi[1], ahi[2], ahi[3]};
                const f32x4v c = __builtin_amdgcn_mfma_f32_16x16x32_bf16(A, Bh, cz, 0, 0, 0);
                yreg[i++] = make_uint2(bf16pair(c[0], c[1]), bf16pair(c[2], c[3]));
            }
        }
    }

    // ---- Pass 1 -> pass 2 hand-off: in-wave transpose via shuffles (R14).
    // Lane (q,n) needs Y rows nt*16+8q+{0..7} of col n = dwords of lanes
    // srcA=((q&1)<<5)+n (rows 8(q&1)+{0..3}) and srcB=srcA+16 (+4..7), from
    // row-tile mt = nt + (q>>1). Shuffle both candidate tiles, cndmask after.
    const int srcA = ((q & 1) << 5) + n15;
    const int srcB = srcA + 16;
    const bool hi = (q >= 2);

    // ---- MFMA pass 2: vertical conv, fragments from shuffles.
    f32x4v accv[2][5];
    {
        const f32x4v cz = {0.f, 0.f, 0.f, 0.f};
        #pragma unroll
        for (int a = 0; a < 5; ++a) {
            int sA0[3], sA1[3], sB0[3], sB1[3];
            #pragma unroll
            for (int mt = 0; mt < 3; ++mt) {
                const uint2 y = yreg[a * 3 + mt];
                sA0[mt] = __shfl((int)y.x, srcA, 64);
                sA1[mt] = __shfl((int)y.y, srcA, 64);
                sB0[mt] = __shfl((int)y.x, srcB, 64);
                sB1[mt] = __shfl((int)y.y, srcB, 64);
            }
            #pragma unroll
            for (int nt = 0; nt < 2; ++nt) {
                union { int u[4]; bf16x8 f; } A;
                A.u[0] = hi ? sA0[nt + 1] : sA0[nt];
                A.u[1] = hi ? sA1[nt + 1] : sA1[nt];
                A.u[2] = hi ? sB0[nt + 1] : sB0[nt];
                A.u[3] = hi ? sB1[nt + 1] : sB1[nt];
                accv[nt][a] = __builtin_amdgcn_mfma_f32_16x16x32_bf16(A.f, Bv, cz, 0, 0, 0);
            }
        }
    }

    // ---- SSIM on 8 pixels/lane (2 n-tiles x 4 cols), fp32 ----
    float lsum = 0.f;
    #pragma unroll
    for (int nt = 0; nt < 2; ++nt) {
        const f32x4v m1 = accv[nt][0], m2 = accv[nt][1];
        const f32x4v epp = accv[nt][2], ett = accv[nt][3], ept = accv[nt][4];
        const f32x4v m1s = m1 * m1, m2s = m2 * m2, m12 = m1 * m2;
        const f32x4v num = (2.f * m12 + 1e-4f) * (2.f * (ept - m12) + 9e-4f);
        const f32x4v den = (m1s + m2s + 1e-4f) * ((epp - m1s) + (ett - m2s) + 9e-4f);
        lsum += num[0] * __builtin_amdgcn_rcpf(den[0]);
        lsum += num[1] * __builtin_amdgcn_rcpf(den[1]);
        lsum += num[2] * __builtin_amdgcn_rcpf(den[2]);
        lsum += num[3] * __builtin_amdgcn_rcpf(den[3]);
    }

    // ---- Block reduction -> one double atomic per block, slot spread over
    // 64 cache lines (R15) ----
    #pragma unroll
    for (int off = 32; off > 0; off >>= 1)
        lsum += __shfl_down(lsum, off, 64);
    if (lane == 0) wave_part[wv] = lsum;
    __syncthreads();
    if (tid == 0) {
        const float bs = wave_part[0] + wave_part[1] + wave_part[2] + wave_part[3];
        const int lid = blockIdx.x + NBX * (blockIdx.y + NBY * (int)blockIdx.z);
        atomicAdd(acc + (lid & slotmask) * 8, (double)bs);
    }
}

__global__ void ssim_final(const double* __restrict__ acc, float* __restrict__ out,
                           int slotmask) {
    if (threadIdx.x == 0) {
        double s = 0.0;
        for (int i = 0; i <= slotmask; ++i) s += acc[i * 8];
        const double n = (double)N_IMG * (double)IMG_H * (double)IMG_W;
        out[0] = (float)(1.0 - s / n);
    }
}

extern "C" void kernel_launch(void* const* d_in, const int* in_sizes, int n_in,
                              void* d_out, int out_size, void* d_ws, size_t ws_size,
                              hipStream_t stream) {
    const float* pred = (const float*)d_in[0];
    const float* targ = (const float*)d_in[1];
    float* out  = (float*)d_out;
    double* acc = (double*)d_ws;

    // R15: 64 atomic slots, 64B apart (4KB) when ws allows; else legacy 1 slot.
    const int nslots = (ws_size >= (size_t)(64 * 64)) ? 64 : 1;
    const int slotmask = nslots - 1;

    hipLaunchKernelGGL(ssim_zero_acc, dim3(1), dim3(64), 0, stream, acc, slotmask);
    dim3 grid(NBX, NBY, N_IMG);   // (8, 16, 48)
    hipLaunchKernelGGL(ssim_main, grid, dim3(256), 0, stream, pred, targ, acc, slotmask);
    hipLaunchKernelGGL(ssim_final, dim3(1), dim3(1), 0, stream, acc, out, slotmask);
}

// Round 9
// 147.846 us; speedup vs baseline: 1.0857x; 1.0857x over previous
//
#include <hip/hip_runtime.h>

#define IMG_W 512
#define IMG_H 512
#define N_IMG 48            // 16 batch * 3 channels
#define TILE_W 64
#define TILE_H 32           // R13: keep 32 (R12's 16 was +75% dur).
#define RAD 5
#define XROWS 48            // 42 halo rows padded to 3 m-tiles of 16
#define XCOLS 84            // R9: 168B row stride -> 16 distinct read start-banks.
#define NBX (IMG_W / TILE_W)   // 8
#define NBY (IMG_H / TILE_H)   // 16

typedef float f32x4v __attribute__((ext_vector_type(4)));
typedef short bf16x8 __attribute__((ext_vector_type(8)));

// R16: fp32x2 -> packed bf16x2 in 3 VALU ops (2 adds + v_perm_b32).
// Round-half-up: same 0.5-ulp bound as RNE. All packed values finite
// non-negative (<~1.2) so +0x8000 can't carry into inf/NaN. No inline asm.
__device__ inline unsigned int bf16pair(float a, float b) {
    const unsigned int ua = __float_as_uint(a) + 0x8000u;
    const unsigned int ub = __float_as_uint(b) + 0x8000u;
    return __builtin_amdgcn_perm(ub, ua, 0x07060302u);
}

// Scalar RNE (make_frag only — off the hot path).
__device__ inline short bf16r(float a) {
    unsigned int u = __float_as_uint(a);
    u = (u + 0x7fffu + ((u >> 16) & 1u)) >> 16;
    return (short)u;
}

// R10/R11: fragment build via closed form (no ssum loop, no divide):
//   w(d) = exp2(-(d-5)^2 * log2e/4.5) * (1/ssum), constants folded.
__device__ inline bf16x8 make_frag(int dbase) {
    bf16x8 f;
    #pragma unroll
    for (int j = 0; j < 8; ++j) {
        const int d = dbase + j;
        const float x = (float)(d - 5);
        const float w = exp2f(-0.32059890f * x * x) * 0.26601246f;
        f[j] = bf16r((d >= 0 && d <= 10) ? w : 0.f);
    }
    return f;
}

// R15: acc is up to 64 slots, each on its own 64B cache line.
__global__ void ssim_zero_acc(double* acc, int slotmask) {
    const int i = threadIdx.x;
    if (i <= slotmask) acc[i * 8] = 0.0;
}

// NOTE 1 (R3/R4 vs R5): NO __threadfence / fold-in finalize.
// NOTE 2 (R8): both 11-tap convs on MFMA; banded Gaussian weights in B.
// NOTE 3 (R14): YT round-trip deleted; pass1->pass2 is an in-wave shuffle
// transpose, ONE barrier.
// NOTE 4 (R15): atomic spread over 64 cache lines (-33 us).
// NOTE 5 (R16): perm-based 3-op bf16 pack (-7 us, VALU 66->55%).
// NOTE 6 (R17): stage ONLY {p,t} in LDS (16.2 KB, was 40.4). pp/tt/pt MFMA
// A-fragments are ELEMENTWISE in p,t -> computed in-register in pass 1
// (unpack is exact shl/and; bf16xbf16 product is exact in f32; perm repack).
// LDS was the occupancy cap: 4 -> 8 blocks/CU (runtime; launch_bounds (256,6)
// keeps VGPR cap 85, no spill risk; if alloc <=64 HW gives 8 anyway).
// R16 counters showed VALU 55% / all else idle at 16 waves/CU: latency-bound,
// residency is the remaining lever.
__global__ __launch_bounds__(256, 6)
void ssim_main(const float* __restrict__ pred, const float* __restrict__ targ,
               double* __restrict__ acc, int slotmask)
{
    __shared__ __align__(16) unsigned short Xp[XROWS][XCOLS];
    __shared__ __align__(16) unsigned short Xt[XROWS][XCOLS];
    __shared__ float wave_part[4];

    const int tid  = threadIdx.x;
    const int lane = tid & 63;
    const int wv   = tid >> 6;     // wave 0..3
    const int n15  = lane & 15;
    const int q    = lane >> 4;    // 0..3

    const int col0 = blockIdx.x * TILE_W;
    const int row0 = blockIdx.y * TILE_H;
    const bool edge = (blockIdx.x == 0) || (blockIdx.x == NBX - 1);
    const long img = blockIdx.z;
    const float* __restrict__ p = pred + img * (long)(IMG_H * IMG_W);
    const float* __restrict__ t = targ + img * (long)(IMG_H * IMG_W);

    // ---- Phase 0a: issue ALL staging loads (4 slots x {p,t} float4).
    float pv[4][4], tv[4][4];
    #pragma unroll
    for (int s = 0; s < 4; ++s) {
        const int idx = tid + s * 256;
        #pragma unroll
        for (int e = 0; e < 4; ++e) { pv[s][e] = 0.f; tv[s][e] = 0.f; }
        if (idx < XROWS * 20) {
            const int r = idx / 20;
            const int g = idx - r * 20;
            const int gr  = row0 - RAD + r;
            const int gcb = col0 - 8 + 4 * g;
            if (gr >= 0 && gr < IMG_H) {
                const float* __restrict__ prow = p + (long)gr * IMG_W;
                const float* __restrict__ trow = t + (long)gr * IMG_W;
                if (!edge || (gcb >= 0 && gcb + 4 <= IMG_W)) {
                    const float4 a = *(const float4*)&prow[gcb];
                    const float4 b = *(const float4*)&trow[gcb];
                    pv[s][0] = a.x; pv[s][1] = a.y; pv[s][2] = a.z; pv[s][3] = a.w;
                    tv[s][0] = b.x; tv[s][1] = b.y; tv[s][2] = b.z; tv[s][3] = b.w;
                } else {
                    #pragma unroll
                    for (int e = 0; e < 4; ++e) {
                        const int c = gcb + e;
                        if (c >= 0 && c < IMG_W) { pv[s][e] = prow[c]; tv[s][e] = trow[c]; }
                    }
                }
            }
        }
    }

    // B fragments — independent VALU work between load issue and use.
    const bf16x8 Bh = make_frag(q * 8 - n15 - 3);
    const bf16x8 Bv = make_frag(q * 8 - n15);

    // ---- Phase 0b: convert + LDS write ({p,t} only, R17). Every element of
    // cols 0..79 is written (finite) — MFMA reads the full footprint.
    #pragma unroll
    for (int s = 0; s < 4; ++s) {
        const int idx = tid + s * 256;
        if (idx < XROWS * 20) {
            const int r = idx / 20;
            const int g = idx - r * 20;
            const float* P = pv[s];
            const float* T = tv[s];
            *(uint2*)&Xp[r][4 * g] = make_uint2(bf16pair(P[0], P[1]), bf16pair(P[2], P[3]));
            *(uint2*)&Xt[r][4 * g] = make_uint2(bf16pair(T[0], T[1]), bf16pair(T[2], T[3]));
        }
    }
    __syncthreads();   // the ONLY full barrier

    // ---- MFMA pass 1: horizontal conv, 5 arrays from 2 staged ones.
    // A[m][k] = X[mt*16+m][wv*16+k]; pp/tt/pt fragments derived in-register:
    // per dword, lo = u<<16 and hi = u&0xffff0000 are EXACT bf16->f32; the
    // f32 product of two bf16s is exact; perm-pack rounds once (0.5 ulp).
    // D[m][n] = Y[mt*16+m][outcol wv*16+n]; lane (q,n) gets rows q*4+{0..3}
    // of col n, packed as 2 bf16-pair dwords, held in regs (no LDS).
    uint2 yreg[15];
    {
        const f32x4v cz = {0.f, 0.f, 0.f, 0.f};
        #pragma unroll
        for (int mt = 0; mt < 3; ++mt) {
            const int row = mt * 16 + n15;
            const int c0  = wv * 16 + 8 * q;
            const uint2 lp = *(const uint2*)&Xp[row][c0];
            const uint2 hp = *(const uint2*)&Xp[row][c0 + 4];
            const uint2 lt = *(const uint2*)&Xt[row][c0];
            const uint2 ht = *(const uint2*)&Xt[row][c0 + 4];
            const unsigned int pd[4] = {lp.x, lp.y, hp.x, hp.y};
            const unsigned int td[4] = {lt.x, lt.y, ht.x, ht.y};
            unsigned int ppd[4], ttd[4], ptd[4];
            #pragma unroll
            for (int j = 0; j < 4; ++j) {
                const float pl = __uint_as_float(pd[j] << 16);
                const float ph = __uint_as_float(pd[j] & 0xffff0000u);
                const float tl = __uint_as_float(td[j] << 16);
                const float th = __uint_as_float(td[j] & 0xffff0000u);
                ppd[j] = bf16pair(pl * pl, ph * ph);
                ttd[j] = bf16pair(tl * tl, th * th);
                ptd[j] = bf16pair(pl * tl, ph * th);
            }
            union U { unsigned int u[4]; bf16x8 f; };
            const U Ap  = {{pd[0], pd[1], pd[2], pd[3]}};
            const U At  = {{td[0], td[1], td[2], td[3]}};
            const U App = {{ppd[0], ppd[1], ppd[2], ppd[3]}};
            const U Att = {{ttd[0], ttd[1], ttd[2], ttd[3]}};
            const U Apt = {{ptd[0], ptd[1], ptd[2], ptd[3]}};
            const f32x4v c0v = __builtin_amdgcn_mfma_f32_16x16x32_bf16(Ap.f,  Bh, cz, 0, 0, 0);
            const f32x4v c1v = __builtin_amdgcn_mfma_f32_16x16x32_bf16(At.f,  Bh, cz, 0, 0, 0);
            const f32x4v c2v = __builtin_amdgcn_mfma_f32_16x16x32_bf16(App.f, Bh, cz, 0, 0, 0);
            const f32x4v c3v = __builtin_amdgcn_mfma_f32_16x16x32_bf16(Att.f, Bh, cz, 0, 0, 0);
            const f32x4v c4v = __builtin_amdgcn_mfma_f32_16x16x32_bf16(Apt.f, Bh, cz, 0, 0, 0);
            yreg[0 * 3 + mt] = make_uint2(bf16pair(c0v[0], c0v[1]), bf16pair(c0v[2], c0v[3]));
            yreg[1 * 3 + mt] = make_uint2(bf16pair(c1v[0], c1v[1]), bf16pair(c1v[2], c1v[3]));
            yreg[2 * 3 + mt] = make_uint2(bf16pair(c2v[0], c2v[1]), bf16pair(c2v[2], c2v[3]));
            yreg[3 * 3 + mt] = make_uint2(bf16pair(c3v[0], c3v[1]), bf16pair(c3v[2], c3v[3]));
            yreg[4 * 3 + mt] = make_uint2(bf16pair(c4v[0], c4v[1]), bf16pair(c4v[2], c4v[3]));
        }
    }

    // ---- Pass 1 -> pass 2 hand-off: in-wave transpose via shuffles (R14).
    // Lane (q,n) needs Y rows nt*16+8q+{0..7} of col n = dwords of lanes
    // srcA=((q&1)<<5)+n and srcB=srcA+16, from row-tile mt = nt + (q>>1).
    const int srcA = ((q & 1) << 5) + n15;
    const int srcB = srcA + 16;
    const bool hi = (q >= 2);

    // ---- MFMA pass 2: vertical conv, fragments from shuffles.
    f32x4v accv[2][5];
    {
        const f32x4v cz = {0.f, 0.f, 0.f, 0.f};
        #pragma unroll
        for (int a = 0; a < 5; ++a) {
            int sA0[3], sA1[3], sB0[3], sB1[3];
            #pragma unroll
            for (int mt = 0; mt < 3; ++mt) {
                const uint2 y = yreg[a * 3 + mt];
                sA0[mt] = __shfl((int)y.x, srcA, 64);
                sA1[mt] = __shfl((int)y.y, srcA, 64);
                sB0[mt] = __shfl((int)y.x, srcB, 64);
                sB1[mt] = __shfl((int)y.y, srcB, 64);
            }
            #pragma unroll
            for (int nt = 0; nt < 2; ++nt) {
                union { int u[4]; bf16x8 f; } A;
                A.u[0] = hi ? sA0[nt + 1] : sA0[nt];
                A.u[1] = hi ? sA1[nt + 1] : sA1[nt];
                A.u[2] = hi ? sB0[nt + 1] : sB0[nt];
                A.u[3] = hi ? sB1[nt + 1] : sB1[nt];
                accv[nt][a] = __builtin_amdgcn_mfma_f32_16x16x32_bf16(A.f, Bv, cz, 0, 0, 0);
            }
        }
    }

    // ---- SSIM on 8 pixels/lane (2 n-tiles x 4 cols), fp32 ----
    float lsum = 0.f;
    #pragma unroll
    for (int nt = 0; nt < 2; ++nt) {
        const f32x4v m1 = accv[nt][0], m2 = accv[nt][1];
        const f32x4v epp = accv[nt][2], ett = accv[nt][3], ept = accv[nt][4];
        const f32x4v m1s = m1 * m1, m2s = m2 * m2, m12 = m1 * m2;
        const f32x4v num = (2.f * m12 + 1e-4f) * (2.f * (ept - m12) + 9e-4f);
        const f32x4v den = (m1s + m2s + 1e-4f) * ((epp - m1s) + (ett - m2s) + 9e-4f);
        lsum += num[0] * __builtin_amdgcn_rcpf(den[0]);
        lsum += num[1] * __builtin_amdgcn_rcpf(den[1]);
        lsum += num[2] * __builtin_amdgcn_rcpf(den[2]);
        lsum += num[3] * __builtin_amdgcn_rcpf(den[3]);
    }

    // ---- Block reduction -> one double atomic per block, 64 slots (R15) ----
    #pragma unroll
    for (int off = 32; off > 0; off >>= 1)
        lsum += __shfl_down(lsum, off, 64);
    if (lane == 0) wave_part[wv] = lsum;
    __syncthreads();
    if (tid == 0) {
        const float bs = wave_part[0] + wave_part[1] + wave_part[2] + wave_part[3];
        const int lid = blockIdx.x + NBX * (blockIdx.y + NBY * (int)blockIdx.z);
        atomicAdd(acc + (lid & slotmask) * 8, (double)bs);
    }
}

__global__ void ssim_final(const double* __restrict__ acc, float* __restrict__ out,
                           int slotmask) {
    if (threadIdx.x == 0) {
        double s = 0.0;
        for (int i = 0; i <= slotmask; ++i) s += acc[i * 8];
        const double n = (double)N_IMG * (double)IMG_H * (double)IMG_W;
        out[0] = (float)(1.0 - s / n);
    }
}

extern "C" void kernel_launch(void* const* d_in, const int* in_sizes, int n_in,
                              void* d_out, int out_size, void* d_ws, size_t ws_size,
                              hipStream_t stream) {
    const float* pred = (const float*)d_in[0];
    const float* targ = (const float*)d_in[1];
    float* out  = (float*)d_out;
    double* acc = (double*)d_ws;

    // R15: 64 atomic slots, 64B apart (4KB) when ws allows; else legacy 1 slot.
    const int nslots = (ws_size >= (size_t)(64 * 64)) ? 64 : 1;
    const int slotmask = nslots - 1;

    hipLaunchKernelGGL(ssim_zero_acc, dim3(1), dim3(64), 0, stream, acc, slotmask);
    dim3 grid(NBX, NBY, N_IMG);   // (8, 16, 48)
    hipLaunchKernelGGL(ssim_main, grid, dim3(256), 0, stream, pred, targ, acc, slotmask);
    hipLaunchKernelGGL(ssim_final, dim3(1), dim3(1), 0, stream, acc, out, slotmask);
}